// Round 10
// baseline (360.631 us; speedup 1.0000x reference)
//
#include <hip/hip_runtime.h>
#include <stdint.h>

#define T_TOKENS 8192
#define D_DIM 512
#define F_DIM 2048
#define E_NUM 8

typedef short short8 __attribute__((ext_vector_type(8)));
typedef short s16x4 __attribute__((ext_vector_type(4)));
typedef float f32x4 __attribute__((ext_vector_type(4)));

// ---------------- bf16 helpers (RNE, finite inputs) -------------------------
__device__ __forceinline__ unsigned short f2bf(float f) {
    union { float f; unsigned int u; } c; c.f = f;
    unsigned int u = c.u;
    unsigned int r = (u + 0x7fffu + ((u >> 16) & 1u)) >> 16;
    return (unsigned short)r;
}
__device__ __forceinline__ unsigned int pack2(float a, float b) {
    return (unsigned int)f2bf(a) | ((unsigned int)f2bf(b) << 16);
}
// fast gelu via native exp2 (log2e folded into poly) + v_rcp; |err| < 1e-3 abs
__device__ __forceinline__ float gelu_fast(float h) {
    float a = h * fmaf(h * h, -0.1029433f, -2.3022141f);  // -2u*log2(e)
    return h * __builtin_amdgcn_rcpf(1.f + __builtin_amdgcn_exp2f(a));
}

// ws layout (bytes). Padded-slot capacity: sum_e ceil128(cnt_e) <= 16384+8*127
#define SLOT_CAP 17408
#define WS_COUNT 0
#define WS_PROBS 512
#define WS_TOK   16384
#define WS_WGT   (WS_TOK + E_NUM * T_TOKENS * 4)
#define WS_INV   (WS_WGT + E_NUM * T_TOKENS * 4)
#define WS_W1B   (1ull << 20)
#define WS_W2B   (WS_W1B + 16777216ull)
#define WS_XG    (WS_W2B + 16777216ull)
#define WS_HG    (WS_XG + (unsigned long long)SLOT_CAP * D_DIM * 2)
#define WS_OG    (WS_HG + (unsigned long long)SLOT_CAP * F_DIM * 2)
#define OG_BYTES ((unsigned long long)SLOT_CAP * D_DIM * 4)
// single-Og end ~159.4 MB; K-split needs WS_OG + 2*OG_BYTES ~195 MB (runtime-gated)

// prefix offsets over 128-padded per-expert counts; also total padded slots
__device__ __forceinline__ void expert_off(const int* __restrict__ count, int e,
                                           int& off_e, int& cnt_e, int& total) {
    int off = 0, ce = 0, tot = 0;
#pragma unroll
    for (int i = 0; i < E_NUM; ++i) {
        int c = count[i];
        int p = (c + 127) & ~127;
        if (i == e) ce = c;
        if (i < e) off += p;
        tot += p;
    }
    off_e = off; cnt_e = ce; total = tot;
}

// ---------------------------------------------------------------------------
// Convert w1/w2 fp32 -> bf16, K-OUTER B-fragment order:
//   frag idx16 = ((e*Ks + ks)*(N/16) + ft)*64 + L
// Also zeroes count[], probs_g[].
// ---------------------------------------------------------------------------
__global__ __launch_bounds__(256) void moe_convert(
    const float* __restrict__ w1, const float* __restrict__ w2,
    unsigned short* __restrict__ w1b, unsigned short* __restrict__ w2b,
    int* __restrict__ count, float* __restrict__ probs_g)
{
    __shared__ float ts[32][65];
    int tid = threadIdx.x;
    if (blockIdx.x == 0 && tid < E_NUM) { count[tid] = 0; probs_g[tid] = 0.f; }

    int b = blockIdx.x;
    bool is2 = b >= 4096;
    int o = is2 ? b - 4096 : b;
    int e = o >> 9, r = o & 511;
    int N  = is2 ? 512 : 2048;
    int Ks = is2 ? 64 : 16;
    int ng, ks;
    if (!is2) { ng = r & 31; ks = r >> 5; }
    else      { ng = r & 7;  ks = r >> 3; }

    const float* src = (is2 ? w2 : w1) + ((size_t)e << 20) + (size_t)(ks * 32) * N + ng * 64;
    int row = tid >> 3, c4 = (tid & 7) * 4;
    f32x4 v0 = *(const f32x4*)(src + (size_t)row * N + c4);
    f32x4 v1 = *(const f32x4*)(src + (size_t)row * N + c4 + 32);
    *(f32x4*)&ts[row][c4] = v0;
    *(f32x4*)&ts[row][c4 + 32] = v1;
    __syncthreads();

    int f = tid >> 6, L = tid & 63, q = L >> 4, n = L & 15;
    float v[8];
#pragma unroll
    for (int j = 0; j < 8; ++j) v[j] = ts[q * 8 + j][f * 16 + n];
    uint4 pk;
    pk.x = pack2(v[0], v[1]); pk.y = pack2(v[2], v[3]);
    pk.z = pack2(v[4], v[5]); pk.w = pack2(v[6], v[7]);
    size_t fraglane = ((size_t)((e * Ks + ks) * (N / 16) + ng * 4 + f)) * 64 + L;
    unsigned short* dst = (is2 ? w2b : w1b) + fraglane * 8;
    *(uint4*)dst = pk;
}

// ---------------------------------------------------------------------------
// Router. Also emits per-token inverse map inv[t*2+k] = (e<<16)|global_slot.
// ---------------------------------------------------------------------------
__global__ __launch_bounds__(256) void moe_router(
    const float* __restrict__ x, const float* __restrict__ gw,
    int* __restrict__ count, int* __restrict__ tok_list,
    float* __restrict__ wgt_list, float* __restrict__ probs_g,
    int* __restrict__ inv)
{
    __shared__ float pprob[E_NUM];
    __shared__ int   lcnt[E_NUM];
    __shared__ int   gbase[E_NUM];
    __shared__ int   ltok[E_NUM][64];
    __shared__ float lwgt[E_NUM][64];
    __shared__ unsigned char re1[32], re2[32];
    __shared__ short rs1[32], rs2[32];

    int tid = threadIdx.x;
    if (tid < E_NUM) { pprob[tid] = 0.f; lcnt[tid] = 0; }
    __syncthreads();

    int wv = tid >> 6, lane = tid & 63;

    float gr[64];
    {
        const f32x4* gp = (const f32x4*)(gw + lane * 64);
#pragma unroll
        for (int i = 0; i < 16; ++i) *(f32x4*)&gr[i * 4] = gp[i];
    }

    float wps[E_NUM];
#pragma unroll
    for (int e = 0; e < E_NUM; ++e) wps[e] = 0.f;

#pragma unroll 1
    for (int i = 0; i < 8; ++i) {
        int t = blockIdx.x * 32 + wv * 8 + i;
        const float* xp = x + (size_t)t * D_DIM + lane * 8;
        f32x4 x0 = *(const f32x4*)xp;
        f32x4 x1 = *(const f32x4*)(xp + 4);
        float xv[8] = { x0.x, x0.y, x0.z, x0.w, x1.x, x1.y, x1.z, x1.w };
        float acc[E_NUM];
#pragma unroll
        for (int e = 0; e < E_NUM; ++e) acc[e] = 0.f;
#pragma unroll
        for (int j = 0; j < 8; ++j)
#pragma unroll
            for (int e = 0; e < E_NUM; ++e) acc[e] += xv[j] * gr[j * 8 + e];
#pragma unroll
        for (int off = 1; off < 64; off <<= 1)
#pragma unroll
            for (int e = 0; e < E_NUM; ++e) acc[e] += __shfl_xor(acc[e], off);

        float m = acc[0];
#pragma unroll
        for (int e = 1; e < E_NUM; ++e) m = fmaxf(m, acc[e]);
        float p[E_NUM], s = 0.f;
#pragma unroll
        for (int e = 0; e < E_NUM; ++e) { p[e] = __expf(acc[e] - m); s += p[e]; }
        float invs = 1.f / s;
#pragma unroll
        for (int e = 0; e < E_NUM; ++e) { p[e] *= invs; wps[e] += p[e]; }

        int e1 = 0;
#pragma unroll
        for (int e = 1; e < E_NUM; ++e) if (p[e] > p[e1]) e1 = e;
        int e2 = (e1 == 0) ? 1 : 0;
#pragma unroll
        for (int e = 0; e < E_NUM; ++e) if (e != e1 && p[e] > p[e2]) e2 = e;

        if (lane == 0) {
            float invw = 1.f / (p[e1] + p[e2]);
            int s1 = atomicAdd(&lcnt[e1], 1); ltok[e1][s1] = t; lwgt[e1][s1] = p[e1] * invw;
            int s2 = atomicAdd(&lcnt[e2], 1); ltok[e2][s2] = t; lwgt[e2][s2] = p[e2] * invw;
            int li = wv * 8 + i;
            re1[li] = (unsigned char)e1; rs1[li] = (short)s1;
            re2[li] = (unsigned char)e2; rs2[li] = (short)s2;
        }
    }
    if (lane == 0) {
#pragma unroll
        for (int e = 0; e < E_NUM; ++e) atomicAdd(&pprob[e], wps[e]);
    }
    __syncthreads();
    if (tid < E_NUM) {
        gbase[tid] = atomicAdd(&count[tid], lcnt[tid]);
        atomicAdd(&probs_g[tid], pprob[tid]);
    }
    __syncthreads();
    if (tid < 32) {
        int t = blockIdx.x * 32 + tid;
        inv[t * 2]     = ((int)re1[tid] << 16) | (gbase[re1[tid]] + rs1[tid]);
        inv[t * 2 + 1] = ((int)re2[tid] << 16) | (gbase[re2[tid]] + rs2[tid]);
    }
    int ee = tid >> 5;
    for (int ss = tid & 31; ss < lcnt[ee]; ss += 32) {
        int dst = ee * T_TOKENS + gbase[ee] + ss;
        tok_list[dst] = ltok[ee][ss];
        wgt_list[dst] = lwgt[ee][ss];
    }
}

// ---------------------------------------------------------------------------
// Gather: expert-ordered Xg (bf16, A-frag order), K-OUTER:
//   idx16 = (kb*ns16 + slot16)*64 + lane;  lane = (m&15) + 16*((k>>3)&3)
// ---------------------------------------------------------------------------
__global__ __launch_bounds__(256) void moe_gather(
    const float* __restrict__ x, const int* __restrict__ count,
    const int* __restrict__ tok_list, unsigned short* __restrict__ Xg,
    const float* __restrict__ probs_g, float* __restrict__ y)
{
    if (blockIdx.x == 0 && threadIdx.x == 0) {
        float s = 0.f;
#pragma unroll
        for (int i = 0; i < E_NUM; ++i) {
            float m = probs_g[i] / (float)T_TOKENS;
            s += m * m;
        }
        y[(size_t)T_TOKENS * D_DIM] = (float)E_NUM * s;
    }

    int e = blockIdx.x & 7, tile = blockIdx.x >> 3;
    int off_e, cnt, total;
    expert_off(count, e, off_e, cnt, total);
    int ns16 = total >> 4;
    int padcnt = (cnt + 127) & ~127;
    if (tile * 64 >= padcnt) return;

    int tid = threadIdx.x;
    int tl = tid >> 2;               // slot in tile 0..63
    int kq = tid & 3;                // 128-k quarter
    int slot = tile * 64 + tl;
    bool valid = slot < cnt;
    int tok = valid ? tok_list[e * T_TOKENS + slot] : 0;
    const float* xr = x + (size_t)tok * D_DIM + kq * 128;
    int base16 = ((off_e + tile * 64) >> 4) + (tl >> 4);
    int mlane = tl & 15;

#pragma unroll 4
    for (int g = 0; g < 16; ++g) {
        uint4 pk;
        if (valid) {
            f32x4 v0 = *(const f32x4*)(xr + g * 8);
            f32x4 v1 = *(const f32x4*)(xr + g * 8 + 4);
            pk.x = pack2(v0.x, v0.y); pk.y = pack2(v0.z, v0.w);
            pk.z = pack2(v1.x, v1.y); pk.w = pack2(v1.z, v1.w);
        } else {
            pk.x = 0; pk.y = 0; pk.z = 0; pk.w = 0;
        }
        int kb = kq * 4 + (g >> 2);
        int lane = mlane + 16 * (g & 3);
        *(uint4*)(Xg + ((size_t)(kb * ns16 + base16) * 64 + lane) * 8) = pk;
    }
}

// ---------------------------------------------------------------------------
// GEMM1: Hg = gelu(Xg @ W1 + b1).  Block 128x256, wave 64x128 (acc[8][4]) —
// 2x arithmetic intensity per L1 byte vs 64x64 (12KB loads -> 32 MFMA/K-step).
// K-OUTER layouts, imm-offset frag loads, one pointer bump per operand/step.
// XCD-chunked swizzle (512 blocks/XCD = one expert), nt innermost.
// SWAPPED operands -> D[f][m]; K-outer pair-interleaved stores -> Hg frag order.
// ---------------------------------------------------------------------------
__global__ __launch_bounds__(256) void moe_gemm1(
    const unsigned short* __restrict__ Xg, const unsigned short* __restrict__ w1b,
    const float* __restrict__ b1, const int* __restrict__ count,
    unsigned short* __restrict__ Hg)
{
    int l = (blockIdx.x & 7) * 512 + (blockIdx.x >> 3);
    int e = l >> 9;
    int rem = l & 511;
    int mt = rem >> 3, nt = rem & 7;          // mt: 128-row tile, nt: 256-col tile
    int off_e, cnt, total;
    expert_off(count, e, off_e, cnt, total);
    int ns16 = total >> 4;
    if (mt * 128 >= cnt) return;

    int tid = threadIdx.x;
    int wv = tid >> 6, lane = tid & 63;
    int wh = wv >> 1, nh = wv & 1;            // wave: 64-row half x 128-col half
    int q = lane >> 4, n = lane & 15;

    int slot16b = (off_e >> 4) + mt * 8 + wh * 4;
    const short8* Ap = (const short8*)Xg + (size_t)slot16b * 64 + lane;
    const short8* Bp = (const short8*)w1b + (size_t)(e * 16 * 128 + nt * 16 + nh * 8) * 64 + lane;
    int astep = ns16 * 64;                    // short8s per K-step
    const int bstep = 128 * 64;

    f32x4 acc[8][4];                          // [j(f-tile)][i(m-tile)]
#pragma unroll
    for (int j = 0; j < 8; ++j)
#pragma unroll
        for (int i = 0; i < 4; ++i) acc[j][i] = (f32x4){0.f, 0.f, 0.f, 0.f};

#pragma unroll 1
    for (int ks = 0; ks < 16; ++ks) {
        short8 A[4], B[8];
#pragma unroll
        for (int i = 0; i < 4; ++i) A[i] = Ap[i * 64];
#pragma unroll
        for (int j = 0; j < 8; ++j) B[j] = Bp[j * 64];
#pragma unroll
        for (int j = 0; j < 8; ++j)
#pragma unroll
            for (int i = 0; i < 4; ++i)
                acc[j][i] = __builtin_amdgcn_mfma_f32_16x16x32_bf16(B[j], A[i], acc[j][i], 0, 0, 0);
        Ap += astep; Bp += bstep;
    }

    // epilogue: lane holds 4 consecutive f (rr) for fixed m -> 8B stores into
    // K-outer Hg frag order.
    s16x4* Hg8 = (s16x4*)Hg;
    int q1 = q >> 1, q0 = q & 1;
#pragma unroll
    for (int j = 0; j < 8; ++j) {
        f32x4 bb = *(const f32x4*)(b1 + e * F_DIM + nt * 256 + nh * 128 + j * 16 + q * 4);
        int ftile = nt * 16 + nh * 8 + j;
        int kbF = ftile >> 1, f1 = ftile & 1;
#pragma unroll
        for (int i = 0; i < 4; ++i) {
            s16x4 sv;
#pragma unroll
            for (int rr = 0; rr < 4; ++rr)
                sv[rr] = (short)f2bf(gelu_fast(acc[j][i][rr] + bb[rr]));
            Hg8[((size_t)(kbF * ns16 + slot16b + i) * 64 + 16 * (2 * f1 + q1) + n) * 2 + q0] = sv;
        }
    }
}

// ---------------------------------------------------------------------------
// GEMM2: Og[slot] = wgt * (Hg @ W2 + b2).  Block 128x256, wave 64x128
// (acc[8][4]); optional K-split x2 (kt0 -> Og0 with +b2, kt1 -> Og1).
// K-OUTER frag layouts; XCD-chunked swizzle.
// ---------------------------------------------------------------------------
__global__ __launch_bounds__(256) void moe_gemm2(
    const unsigned short* __restrict__ Hg, const unsigned short* __restrict__ w2b,
    const float* __restrict__ b2, const int* __restrict__ count,
    const float* __restrict__ wgt_list, float* __restrict__ Og0,
    float* __restrict__ Og1, int ksplit)
{
    int e, kt, mt, nt;
    if (ksplit) {
        int l = (blockIdx.x & 7) * 256 + (blockIdx.x >> 3);
        e = l >> 8;
        int rem = l & 255;
        mt = rem >> 2; nt = (rem >> 1) & 1; kt = rem & 1;
    } else {
        int l = (blockIdx.x & 7) * 128 + (blockIdx.x >> 3);
        e = l >> 7;
        int rem = l & 127;
        mt = rem >> 1; nt = rem & 1; kt = 0;
    }
    int off_e, cnt, total;
    expert_off(count, e, off_e, cnt, total);
    int ns16 = total >> 4;
    if (mt * 128 >= cnt) return;

    __shared__ float swgt[128];

    int tid = threadIdx.x;
    if (tid < 128) {
        int s = mt * 128 + tid;
        swgt[tid] = (s < cnt) ? wgt_list[e * T_TOKENS + s] : 0.f;
    }
    __syncthreads();

    int wv = tid >> 6, lane = tid & 63;
    int wh = wv >> 1, nh = wv & 1;
    int q = lane >> 4, n = lane & 15;

    int nkb = ksplit ? 32 : 64;
    int kb0 = kt * 32;

    int slot16b = (off_e >> 4) + mt * 8 + wh * 4;
    int astep = ns16 * 64;
    const short8* Ap = (const short8*)Hg + (size_t)kb0 * astep + (size_t)slot16b * 64 + lane;
    const short8* Bp = (const short8*)w2b + (size_t)((e * 64 + kb0) * 32 + nt * 16 + nh * 8) * 64 + lane;
    const int bstep = 32 * 64;

    f32x4 acc[8][4];                          // [j(d-tile)][i(m-tile)]
#pragma unroll
    for (int j = 0; j < 8; ++j)
#pragma unroll
        for (int i = 0; i < 4; ++i) acc[j][i] = (f32x4){0.f, 0.f, 0.f, 0.f};

#pragma unroll 1
    for (int kb = 0; kb < nkb; ++kb) {
        short8 A[4], B[8];
#pragma unroll
        for (int i = 0; i < 4; ++i) A[i] = Ap[i * 64];
#pragma unroll
        for (int j = 0; j < 8; ++j) B[j] = Bp[j * 64];
#pragma unroll
        for (int j = 0; j < 8; ++j)
#pragma unroll
            for (int i = 0; i < 4; ++i)
                acc[j][i] = __builtin_amdgcn_mfma_f32_16x16x32_bf16(B[j], A[i], acc[j][i], 0, 0, 0);
        Ap += astep; Bp += bstep;
    }

    // epilogue: lane holds 4 consecutive d for fixed slot m -> f32x4 stores
    float* Og = (kt == 0) ? Og0 : Og1;
#pragma unroll
    for (int j = 0; j < 8; ++j) {
        int d0 = nt * 256 + nh * 128 + j * 16 + q * 4;
        f32x4 bb;
        if (kt == 0) bb = *(const f32x4*)(b2 + e * D_DIM + d0);
        else         bb = (f32x4){0.f, 0.f, 0.f, 0.f};
#pragma unroll
        for (int i = 0; i < 4; ++i) {
            int m = wh * 64 + i * 16 + n;
            float wg = swgt[m];
            f32x4 o;
#pragma unroll
            for (int rr = 0; rr < 4; ++rr) o[rr] = wg * (acc[j][i][rr] + bb[rr]);
            *(f32x4*)(Og + (size_t)(off_e + mt * 128 + m) * D_DIM + d0) = o;
        }
    }
}

// ---------------------------------------------------------------------------
// Combine: y[t] = sum over its 2 expert rows (and 2 K-halves when split).
// ---------------------------------------------------------------------------
__global__ __launch_bounds__(256) void moe_combine(
    const float* __restrict__ Og0, const float* __restrict__ Og1,
    const int* __restrict__ inv, const int* __restrict__ count,
    float* __restrict__ y, int ksplit)
{
    __shared__ int offs[E_NUM];
    int tid = threadIdx.x;
    if (tid < E_NUM) {
        int off = 0;
        for (int i = 0; i < tid; ++i) off += (count[i] + 127) & ~127;
        offs[tid] = off;
    }
    __syncthreads();

    int tk = blockIdx.x * 2 + (tid >> 7);
    int l = tid & 127;
    int i1 = inv[tk * 2], i2 = inv[tk * 2 + 1];
    size_t r1 = (size_t)(offs[i1 >> 16] + (i1 & 0xffff)) * D_DIM;
    size_t r2 = (size_t)(offs[i2 >> 16] + (i2 & 0xffff)) * D_DIM;
    f32x4 a = *((const f32x4*)(Og0 + r1) + l);
    f32x4 b = *((const f32x4*)(Og0 + r2) + l);
    f32x4 o = { a.x + b.x, a.y + b.y, a.z + b.z, a.w + b.w };
    if (ksplit) {
        f32x4 c = *((const f32x4*)(Og1 + r1) + l);
        f32x4 d = *((const f32x4*)(Og1 + r2) + l);
        o.x += c.x + d.x; o.y += c.y + d.y; o.z += c.z + d.z; o.w += c.w + d.w;
    }
    *((f32x4*)(y + (size_t)tk * D_DIM) + l) = o;
}

// ---------------------------------------------------------------------------
extern "C" void kernel_launch(void* const* d_in, const int* in_sizes, int n_in,
                              void* d_out, int out_size, void* d_ws, size_t ws_size,
                              hipStream_t stream) {
    const float* x  = (const float*)d_in[0];
    const float* gw = (const float*)d_in[1];
    const float* w1 = (const float*)d_in[2];
    const float* b1 = (const float*)d_in[3];
    const float* w2 = (const float*)d_in[4];
    const float* b2 = (const float*)d_in[5];
    float* out = (float*)d_out;

    char* ws = (char*)d_ws;
    int*   count     = (int*)(ws + WS_COUNT);
    float* probs_g   = (float*)(ws + WS_PROBS);
    int*   tok_list  = (int*)(ws + WS_TOK);
    float* wgt_list  = (float*)(ws + WS_WGT);
    int*   inv       = (int*)(ws + WS_INV);
    unsigned short* w1b = (unsigned short*)(ws + WS_W1B);
    unsigned short* w2b = (unsigned short*)(ws + WS_W2B);
    unsigned short* Xg  = (unsigned short*)(ws + WS_XG);
    unsigned short* Hg  = (unsigned short*)(ws + WS_HG);
    float*          Og0 = (float*)(ws + WS_OG);
    float*          Og1 = (float*)(ws + WS_OG + OG_BYTES);

    int ksplit = (ws_size >= WS_OG + 2 * OG_BYTES) ? 1 : 0;

    moe_convert<<<8192, 256, 0, stream>>>(w1, w2, w1b, w2b, count, probs_g);
    moe_router<<<T_TOKENS / 32, 256, 0, stream>>>(x, gw, count, tok_list, wgt_list, probs_g, inv);
    moe_gather<<<8 * 128, 256, 0, stream>>>(x, count, tok_list, Xg, probs_g, out);
    moe_gemm1<<<8 * 64 * 8, 256, 0, stream>>>(Xg, w1b, b1, count, Hg);
    moe_gemm2<<<(ksplit ? 2048 : 1024), 256, 0, stream>>>(Hg, w2b, b2, count, wgt_list, Og0, Og1, ksplit);
    moe_combine<<<T_TOKENS / 2, 256, 0, stream>>>(Og0, Og1, inv, count, out, ksplit);
}

// Round 12
// 299.988 us; speedup vs baseline: 1.2022x; 1.2022x over previous
//
#include <hip/hip_runtime.h>
#include <stdint.h>

#define T_TOKENS 8192
#define D_DIM 512
#define F_DIM 2048
#define E_NUM 8

typedef short short8 __attribute__((ext_vector_type(8)));
typedef short s16x4 __attribute__((ext_vector_type(4)));
typedef float f32x4 __attribute__((ext_vector_type(4)));

// ---------------- bf16 helpers (RNE, finite inputs) -------------------------
__device__ __forceinline__ unsigned short f2bf(float f) {
    union { float f; unsigned int u; } c; c.f = f;
    unsigned int u = c.u;
    unsigned int r = (u + 0x7fffu + ((u >> 16) & 1u)) >> 16;
    return (unsigned short)r;
}
__device__ __forceinline__ unsigned int pack2(float a, float b) {
    return (unsigned int)f2bf(a) | ((unsigned int)f2bf(b) << 16);
}
// fast gelu via native exp2 (log2e folded into poly) + v_rcp; |err| < 1e-3 abs
__device__ __forceinline__ float gelu_fast(float h) {
    float a = h * fmaf(h * h, -0.1029433f, -2.3022141f);  // -2u*log2(e)
    return h * __builtin_amdgcn_rcpf(1.f + __builtin_amdgcn_exp2f(a));
}

// ws layout (bytes). Padded-slot capacity: sum_e ceil128(cnt_e) <= 16384+8*127
#define SLOT_CAP 17408
#define WS_COUNT 0
#define WS_PROBS 512
#define WS_TOK   16384
#define WS_WGT   (WS_TOK + E_NUM * T_TOKENS * 4)
#define WS_INV   (WS_WGT + E_NUM * T_TOKENS * 4)
#define WS_W1B   (1ull << 20)
#define WS_W2B   (WS_W1B + 16777216ull)
#define WS_XG    (WS_W2B + 16777216ull)
#define WS_HG    (WS_XG + (unsigned long long)SLOT_CAP * D_DIM * 2)
#define WS_OG    (WS_HG + (unsigned long long)SLOT_CAP * F_DIM * 2)
#define OG_BYTES ((unsigned long long)SLOT_CAP * D_DIM * 4)
// single-Og end ~152 MiB; K-split needs WS_OG + 2*OG_BYTES ~186 MiB (runtime-gated)

// prefix offsets over 128-padded per-expert counts
__device__ __forceinline__ void expert_off(const int* __restrict__ count, int e,
                                           int& off_e, int& cnt_e) {
    int off = 0, ce = 0;
#pragma unroll
    for (int i = 0; i < E_NUM; ++i) {
        int c = count[i];
        if (i == e) ce = c;
        if (i < e) off += (c + 127) & ~127;
    }
    off_e = off; cnt_e = ce;
}

// ---------------------------------------------------------------------------
// Convert w1/w2 fp32 -> bf16 in MFMA B-fragment order:
//   frag-lane linear = ((e*(N/16) + ft)*(K/32) + ks)*64 + L   (short8 units)
// Also zeroes count[], probs_g[].
// ---------------------------------------------------------------------------
__global__ __launch_bounds__(256) void moe_convert(
    const float* __restrict__ w1, const float* __restrict__ w2,
    unsigned short* __restrict__ w1b, unsigned short* __restrict__ w2b,
    int* __restrict__ count, float* __restrict__ probs_g)
{
    __shared__ float ts[32][65];
    int tid = threadIdx.x;
    if (blockIdx.x == 0 && tid < E_NUM) { count[tid] = 0; probs_g[tid] = 0.f; }

    int b = blockIdx.x;
    bool is2 = b >= 4096;
    int o = is2 ? b - 4096 : b;
    int e = o >> 9, r = o & 511;
    int N  = is2 ? 512 : 2048;
    int Ks = is2 ? 64 : 16;
    int ng, ks;
    if (!is2) { ng = r & 31; ks = r >> 5; }
    else      { ng = r & 7;  ks = r >> 3; }

    const float* src = (is2 ? w2 : w1) + ((size_t)e << 20) + (size_t)(ks * 32) * N + ng * 64;
    int row = tid >> 3, c4 = (tid & 7) * 4;
    f32x4 v0 = *(const f32x4*)(src + (size_t)row * N + c4);
    f32x4 v1 = *(const f32x4*)(src + (size_t)row * N + c4 + 32);
    *(f32x4*)&ts[row][c4] = v0;
    *(f32x4*)&ts[row][c4 + 32] = v1;
    __syncthreads();

    int f = tid >> 6, L = tid & 63, q = L >> 4, n = L & 15;
    float v[8];
#pragma unroll
    for (int j = 0; j < 8; ++j) v[j] = ts[q * 8 + j][f * 16 + n];
    uint4 pk;
    pk.x = pack2(v[0], v[1]); pk.y = pack2(v[2], v[3]);
    pk.z = pack2(v[4], v[5]); pk.w = pack2(v[6], v[7]);
    size_t fraglane = ((size_t)((e * (N / 16) + ng * 4 + f) * Ks + ks)) * 64 + L;
    unsigned short* dst = (is2 ? w2b : w1b) + fraglane * 8;
    *(uint4*)dst = pk;
}

// ---------------------------------------------------------------------------
// Router. Also emits per-token inverse map inv[t*2+k] = (e<<16)|global_slot.
// ---------------------------------------------------------------------------
__global__ __launch_bounds__(256) void moe_router(
    const float* __restrict__ x, const float* __restrict__ gw,
    int* __restrict__ count, int* __restrict__ tok_list,
    float* __restrict__ wgt_list, float* __restrict__ probs_g,
    int* __restrict__ inv)
{
    __shared__ float pprob[E_NUM];
    __shared__ int   lcnt[E_NUM];
    __shared__ int   gbase[E_NUM];
    __shared__ int   ltok[E_NUM][64];
    __shared__ float lwgt[E_NUM][64];
    __shared__ unsigned char re1[32], re2[32];
    __shared__ short rs1[32], rs2[32];

    int tid = threadIdx.x;
    if (tid < E_NUM) { pprob[tid] = 0.f; lcnt[tid] = 0; }
    __syncthreads();

    int wv = tid >> 6, lane = tid & 63;

    float gr[64];
    {
        const f32x4* gp = (const f32x4*)(gw + lane * 64);
#pragma unroll
        for (int i = 0; i < 16; ++i) *(f32x4*)&gr[i * 4] = gp[i];
    }

    float wps[E_NUM];
#pragma unroll
    for (int e = 0; e < E_NUM; ++e) wps[e] = 0.f;

#pragma unroll 1
    for (int i = 0; i < 8; ++i) {
        int t = blockIdx.x * 32 + wv * 8 + i;
        const float* xp = x + (size_t)t * D_DIM + lane * 8;
        f32x4 x0 = *(const f32x4*)xp;
        f32x4 x1 = *(const f32x4*)(xp + 4);
        float xv[8] = { x0.x, x0.y, x0.z, x0.w, x1.x, x1.y, x1.z, x1.w };
        float acc[E_NUM];
#pragma unroll
        for (int e = 0; e < E_NUM; ++e) acc[e] = 0.f;
#pragma unroll
        for (int j = 0; j < 8; ++j)
#pragma unroll
            for (int e = 0; e < E_NUM; ++e) acc[e] += xv[j] * gr[j * 8 + e];
#pragma unroll
        for (int off = 1; off < 64; off <<= 1)
#pragma unroll
            for (int e = 0; e < E_NUM; ++e) acc[e] += __shfl_xor(acc[e], off);

        float m = acc[0];
#pragma unroll
        for (int e = 1; e < E_NUM; ++e) m = fmaxf(m, acc[e]);
        float p[E_NUM], s = 0.f;
#pragma unroll
        for (int e = 0; e < E_NUM; ++e) { p[e] = __expf(acc[e] - m); s += p[e]; }
        float invs = 1.f / s;
#pragma unroll
        for (int e = 0; e < E_NUM; ++e) { p[e] *= invs; wps[e] += p[e]; }

        int e1 = 0;
#pragma unroll
        for (int e = 1; e < E_NUM; ++e) if (p[e] > p[e1]) e1 = e;
        int e2 = (e1 == 0) ? 1 : 0;
#pragma unroll
        for (int e = 0; e < E_NUM; ++e) if (e != e1 && p[e] > p[e2]) e2 = e;

        if (lane == 0) {
            float invw = 1.f / (p[e1] + p[e2]);
            int s1 = atomicAdd(&lcnt[e1], 1); ltok[e1][s1] = t; lwgt[e1][s1] = p[e1] * invw;
            int s2 = atomicAdd(&lcnt[e2], 1); ltok[e2][s2] = t; lwgt[e2][s2] = p[e2] * invw;
            int li = wv * 8 + i;
            re1[li] = (unsigned char)e1; rs1[li] = (short)s1;
            re2[li] = (unsigned char)e2; rs2[li] = (short)s2;
        }
    }
    if (lane == 0) {
#pragma unroll
        for (int e = 0; e < E_NUM; ++e) atomicAdd(&pprob[e], wps[e]);
    }
    __syncthreads();
    if (tid < E_NUM) {
        gbase[tid] = atomicAdd(&count[tid], lcnt[tid]);
        atomicAdd(&probs_g[tid], pprob[tid]);
    }
    __syncthreads();
    if (tid < 32) {
        int t = blockIdx.x * 32 + tid;
        inv[t * 2]     = ((int)re1[tid] << 16) | (gbase[re1[tid]] + rs1[tid]);
        inv[t * 2 + 1] = ((int)re2[tid] << 16) | (gbase[re2[tid]] + rs2[tid]);
    }
    int ee = tid >> 5;
    for (int ss = tid & 31; ss < lcnt[ee]; ss += 32) {
        int dst = ee * T_TOKENS + gbase[ee] + ss;
        tok_list[dst] = ltok[ee][ss];
        wgt_list[dst] = lwgt[ee][ss];
    }
}

// ---------------------------------------------------------------------------
// Gather: expert-ordered Xg (bf16, A-frag order), zero-padded to 128 slots.
//   Xg short8-linear = (slot16*16 + kb)*64 + lane; lane = (m&15) + 16*((k>>3)&3)
// ---------------------------------------------------------------------------
__global__ __launch_bounds__(256) void moe_gather(
    const float* __restrict__ x, const int* __restrict__ count,
    const int* __restrict__ tok_list, unsigned short* __restrict__ Xg,
    const float* __restrict__ probs_g, float* __restrict__ y)
{
    if (blockIdx.x == 0 && threadIdx.x == 0) {
        float s = 0.f;
#pragma unroll
        for (int i = 0; i < E_NUM; ++i) {
            float m = probs_g[i] / (float)T_TOKENS;
            s += m * m;
        }
        y[(size_t)T_TOKENS * D_DIM] = (float)E_NUM * s;
    }

    int e = blockIdx.x & 7, tile = blockIdx.x >> 3;
    int off_e, cnt;
    expert_off(count, e, off_e, cnt);
    int padcnt = (cnt + 127) & ~127;
    if (tile * 64 >= padcnt) return;

    int tid = threadIdx.x;
    int tl = tid >> 2;               // slot in tile 0..63
    int kq = tid & 3;                // 128-k quarter
    int slot = tile * 64 + tl;
    bool valid = slot < cnt;
    int tok = valid ? tok_list[e * T_TOKENS + slot] : 0;
    const float* xr = x + (size_t)tok * D_DIM + kq * 128;
    int base16 = ((off_e + tile * 64) >> 4) + (tl >> 4);
    int mlane = tl & 15;

#pragma unroll 4
    for (int g = 0; g < 16; ++g) {
        uint4 pk;
        if (valid) {
            f32x4 v0 = *(const f32x4*)(xr + g * 8);
            f32x4 v1 = *(const f32x4*)(xr + g * 8 + 4);
            pk.x = pack2(v0.x, v0.y); pk.y = pack2(v0.z, v0.w);
            pk.z = pack2(v1.x, v1.y); pk.w = pack2(v1.z, v1.w);
        } else {
            pk.x = 0; pk.y = 0; pk.z = 0; pk.w = 0;
        }
        int kb = kq * 4 + (g >> 2);
        int lane = mlane + 16 * (g & 3);
        *(uint4*)(Xg + ((size_t)(base16 * 16 + kb) * 64 + lane) * 8) = pk;
    }
}

// ---------------------------------------------------------------------------
// GEMM1 (R8 form — best measured): block 128x128, wave 64x64, XCD-chunked
// swizzle with nt innermost; SWAPPED operands -> D[f][m]; pair-interleaved
// 8B stores make Hg bit-identical to standard frag-linear layout.
// ---------------------------------------------------------------------------
__global__ __launch_bounds__(256) void moe_gemm1(
    const unsigned short* __restrict__ Xg, const unsigned short* __restrict__ w1b,
    const float* __restrict__ b1, const int* __restrict__ count,
    unsigned short* __restrict__ Hg)
{
    int l = (blockIdx.x & 7) * 1024 + (blockIdx.x >> 3);
    int e = l >> 10;
    int rem = l & 1023;
    int mt = rem >> 4, nt = rem & 15;
    int off_e, cnt;
    expert_off(count, e, off_e, cnt);
    if (mt * 128 >= cnt) return;

    int tid = threadIdx.x;
    int wv = tid >> 6, lane = tid & 63;
    int wh = wv >> 1, nh = wv & 1;
    int q = lane >> 4, n = lane & 15;

    int slot16b = (off_e >> 4) + mt * 8 + wh * 4;
    const short8* Ap = (const short8*)Xg + (size_t)slot16b * 1024 + lane;
    const short8* Bp = (const short8*)w1b + (size_t)(e * 128 + nt * 8 + nh * 4) * 1024 + lane;

    f32x4 acc[4][4];   // [j(f-tile)][i(m-tile)]
#pragma unroll
    for (int j = 0; j < 4; ++j)
#pragma unroll
        for (int i = 0; i < 4; ++i) acc[j][i] = (f32x4){0.f, 0.f, 0.f, 0.f};

#pragma unroll 2
    for (int ks = 0; ks < 16; ++ks) {
        short8 A[4], B[4];
#pragma unroll
        for (int i = 0; i < 4; ++i) A[i] = Ap[(size_t)i * 1024 + ks * 64];
#pragma unroll
        for (int j = 0; j < 4; ++j) B[j] = Bp[(size_t)j * 1024 + ks * 64];
#pragma unroll
        for (int j = 0; j < 4; ++j)
#pragma unroll
            for (int i = 0; i < 4; ++i)
                acc[j][i] = __builtin_amdgcn_mfma_f32_16x16x32_bf16(B[j], A[i], acc[j][i], 0, 0, 0);
    }

    // epilogue: pack 4 consecutive f (rr) for fixed m -> pair-interleaved 8B store
    s16x4* Hg8 = (s16x4*)Hg;
    int q1 = q >> 1, q0 = q & 1;
#pragma unroll
    for (int j = 0; j < 4; ++j) {
        f32x4 bb = *(const f32x4*)(b1 + e * F_DIM + nt * 128 + nh * 64 + j * 16 + q * 4);
        int ftile = nt * 8 + nh * 4 + j;
#pragma unroll
        for (int i = 0; i < 4; ++i) {
            s16x4 sv;
#pragma unroll
            for (int rr = 0; rr < 4; ++rr)
                sv[rr] = (short)f2bf(gelu_fast(acc[j][i][rr] + bb[rr]));
            Hg8[(size_t)(slot16b + i) * 8192 + ftile * 64 + q1 * 32 + 2 * n + q0] = sv;
        }
    }
}

// ---------------------------------------------------------------------------
// GEMM2: Og[slot] = wgt * (Hg @ W2 + b2).  M-tile 64, N-tile 128, K=2048.
// Changes vs R8: (1) optional K-split x2 (kt0 -> Og0 with +b2, kt1 -> Og1),
// doubling active blocks for latency hiding; (2) A-frag prefetch one K-step
// ahead (A = Hg is the HBM-latency operand; B is L2-resident per expert).
// XCD-chunked swizzle, nt innermost. Plain f32 stores, no atomics.
// ---------------------------------------------------------------------------
__global__ __launch_bounds__(256) void moe_gemm2(
    const unsigned short* __restrict__ Hg, const unsigned short* __restrict__ w2b,
    const float* __restrict__ b2, const int* __restrict__ count,
    const float* __restrict__ wgt_list, float* __restrict__ Og0,
    float* __restrict__ Og1, int ksplit)
{
    int e, kt, mt, nt;
    if (ksplit) {
        int l = (blockIdx.x & 7) * 1024 + (blockIdx.x >> 3);
        e = l >> 10;
        int rem = l & 1023;
        mt = rem >> 3; kt = (rem >> 2) & 1; nt = rem & 3;
    } else {
        int l = (blockIdx.x & 7) * 512 + (blockIdx.x >> 3);
        e = l >> 9;
        int rem = l & 511;
        mt = rem >> 2; kt = 0; nt = rem & 3;
    }
    int off_e, cnt;
    expert_off(count, e, off_e, cnt);
    if (mt * 64 >= cnt) return;

    __shared__ float swgt[64];

    int tid = threadIdx.x;
    if (tid < 64) {
        int s = mt * 64 + tid;
        swgt[tid] = (s < cnt) ? wgt_list[e * T_TOKENS + s] : 0.f;
    }
    __syncthreads();

    int wv = tid >> 6, lane = tid & 63;
    int wh = wv >> 1, nh = wv & 1;
    int q = lane >> 4, n = lane & 15;

    int nkb = ksplit ? 32 : 64;
    int kb0 = kt * 32;

    int slot16b = (off_e >> 4) + mt * 4 + wh * 2;
    const short8* Ap = (const short8*)Hg + (size_t)slot16b * 4096 + kb0 * 64 + lane;
    const short8* Bp = (const short8*)w2b + (size_t)(e * 32 + nt * 8 + nh * 4) * 4096 + kb0 * 64 + lane;

    f32x4 acc[4][2];   // [j(d-tile)][i(m-tile)]
#pragma unroll
    for (int j = 0; j < 4; ++j)
#pragma unroll
        for (int i = 0; i < 2; ++i) acc[j][i] = (f32x4){0.f, 0.f, 0.f, 0.f};

    // A-prefetch pipeline: A for step kb in regs before its MFMAs begin
    short8 Acur0 = Ap[0], Acur1 = Ap[4096];

#pragma unroll 2
    for (int kb = 0; kb < nkb; ++kb) {
        short8 Anxt0, Anxt1;
        if (kb + 1 < nkb) {
            Anxt0 = Ap[(kb + 1) * 64];
            Anxt1 = Ap[4096 + (kb + 1) * 64];
        }
        short8 B[4];
#pragma unroll
        for (int j = 0; j < 4; ++j) B[j] = Bp[(size_t)j * 4096 + kb * 64];
#pragma unroll
        for (int j = 0; j < 4; ++j) {
            acc[j][0] = __builtin_amdgcn_mfma_f32_16x16x32_bf16(B[j], Acur0, acc[j][0], 0, 0, 0);
            acc[j][1] = __builtin_amdgcn_mfma_f32_16x16x32_bf16(B[j], Acur1, acc[j][1], 0, 0, 0);
        }
        if (kb + 1 < nkb) { Acur0 = Anxt0; Acur1 = Anxt1; }
    }

    // epilogue: lane holds 4 consecutive d for fixed slot m -> f32x4 stores
    float* Og = (kt == 0) ? Og0 : Og1;
#pragma unroll
    for (int j = 0; j < 4; ++j) {
        int d0 = nt * 128 + nh * 64 + j * 16 + q * 4;
        f32x4 bb;
        if (kt == 0) bb = *(const f32x4*)(b2 + e * D_DIM + d0);
        else         bb = (f32x4){0.f, 0.f, 0.f, 0.f};
#pragma unroll
        for (int i = 0; i < 2; ++i) {
            int m = wh * 32 + i * 16 + n;
            float wg = swgt[m];
            f32x4 o;
#pragma unroll
            for (int rr = 0; rr < 4; ++rr) o[rr] = wg * (acc[j][i][rr] + bb[rr]);
            *(f32x4*)(Og + (size_t)(off_e + mt * 64 + m) * D_DIM + d0) = o;
        }
    }
}

// ---------------------------------------------------------------------------
// Combine: y[t] = sum over its 2 expert rows (and 2 K-halves when split).
// ---------------------------------------------------------------------------
__global__ __launch_bounds__(256) void moe_combine(
    const float* __restrict__ Og0, const float* __restrict__ Og1,
    const int* __restrict__ inv, const int* __restrict__ count,
    float* __restrict__ y, int ksplit)
{
    __shared__ int offs[E_NUM];
    int tid = threadIdx.x;
    if (tid < E_NUM) {
        int off = 0;
        for (int i = 0; i < tid; ++i) off += (count[i] + 127) & ~127;
        offs[tid] = off;
    }
    __syncthreads();

    int tk = blockIdx.x * 2 + (tid >> 7);
    int l = tid & 127;
    int i1 = inv[tk * 2], i2 = inv[tk * 2 + 1];
    size_t r1 = (size_t)(offs[i1 >> 16] + (i1 & 0xffff)) * D_DIM;
    size_t r2 = (size_t)(offs[i2 >> 16] + (i2 & 0xffff)) * D_DIM;
    f32x4 a = *((const f32x4*)(Og0 + r1) + l);
    f32x4 b = *((const f32x4*)(Og0 + r2) + l);
    f32x4 o = { a.x + b.x, a.y + b.y, a.z + b.z, a.w + b.w };
    if (ksplit) {
        f32x4 c = *((const f32x4*)(Og1 + r1) + l);
        f32x4 d = *((const f32x4*)(Og1 + r2) + l);
        o.x += c.x + d.x; o.y += c.y + d.y; o.z += c.z + d.z; o.w += c.w + d.w;
    }
    *((f32x4*)(y + (size_t)tk * D_DIM) + l) = o;
}

// ---------------------------------------------------------------------------
extern "C" void kernel_launch(void* const* d_in, const int* in_sizes, int n_in,
                              void* d_out, int out_size, void* d_ws, size_t ws_size,
                              hipStream_t stream) {
    const float* x  = (const float*)d_in[0];
    const float* gw = (const float*)d_in[1];
    const float* w1 = (const float*)d_in[2];
    const float* b1 = (const float*)d_in[3];
    const float* w2 = (const float*)d_in[4];
    const float* b2 = (const float*)d_in[5];
    float* out = (float*)d_out;

    char* ws = (char*)d_ws;
    int*   count     = (int*)(ws + WS_COUNT);
    float* probs_g   = (float*)(ws + WS_PROBS);
    int*   tok_list  = (int*)(ws + WS_TOK);
    float* wgt_list  = (float*)(ws + WS_WGT);
    int*   inv       = (int*)(ws + WS_INV);
    unsigned short* w1b = (unsigned short*)(ws + WS_W1B);
    unsigned short* w2b = (unsigned short*)(ws + WS_W2B);
    unsigned short* Xg  = (unsigned short*)(ws + WS_XG);
    unsigned short* Hg  = (unsigned short*)(ws + WS_HG);
    float*          Og0 = (float*)(ws + WS_OG);
    float*          Og1 = (float*)(ws + WS_OG + OG_BYTES);

    int ksplit = (ws_size >= WS_OG + 2 * OG_BYTES) ? 1 : 0;

    moe_convert<<<8192, 256, 0, stream>>>(w1, w2, w1b, w2b, count, probs_g);
    moe_router<<<T_TOKENS / 32, 256, 0, stream>>>(x, gw, count, tok_list, wgt_list, probs_g, inv);
    moe_gather<<<8 * 128, 256, 0, stream>>>(x, count, tok_list, Xg, probs_g, out);
    moe_gemm1<<<8 * 64 * 16, 256, 0, stream>>>(Xg, w1b, b1, count, Hg);
    moe_gemm2<<<(ksplit ? 8192 : 4096), 256, 0, stream>>>(Hg, w2b, b2, count, wgt_list, Og0, Og1, ksplit);
    moe_combine<<<T_TOKENS / 2, 256, 0, stream>>>(Og0, Og1, inv, count, out, ksplit);
}

// Round 13
// 271.829 us; speedup vs baseline: 1.3267x; 1.1036x over previous
//
#include <hip/hip_runtime.h>
#include <stdint.h>

#define T_TOKENS 8192
#define D_DIM 512
#define F_DIM 2048
#define E_NUM 8

typedef short short8 __attribute__((ext_vector_type(8)));
typedef short s16x4 __attribute__((ext_vector_type(4)));
typedef float f32x4 __attribute__((ext_vector_type(4)));

// ---------------- bf16 helpers (RNE, finite inputs) -------------------------
__device__ __forceinline__ unsigned short f2bf(float f) {
    union { float f; unsigned int u; } c; c.f = f;
    unsigned int u = c.u;
    unsigned int r = (u + 0x7fffu + ((u >> 16) & 1u)) >> 16;
    return (unsigned short)r;
}
__device__ __forceinline__ unsigned int pack2(float a, float b) {
    return (unsigned int)f2bf(a) | ((unsigned int)f2bf(b) << 16);
}
// fast gelu via native exp2 (log2e folded into poly) + v_rcp; |err| < 1e-3 abs
__device__ __forceinline__ float gelu_fast(float h) {
    float a = h * fmaf(h * h, -0.1029433f, -2.3022141f);  // -2u*log2(e)
    return h * __builtin_amdgcn_rcpf(1.f + __builtin_amdgcn_exp2f(a));
}
// async global->LDS, 16B/lane: LDS dest = wave-uniform base + lane*16.
__device__ __forceinline__ void gload_lds16(const void* g, void* l) {
    __builtin_amdgcn_global_load_lds(
        (const __attribute__((address_space(1))) void*)g,
        (__attribute__((address_space(3))) void*)l, 16, 0, 0);
}

// ws layout (bytes). Padded-slot capacity: sum_e ceil128(cnt_e) <= 16384+8*127
#define SLOT_CAP 17408
#define WS_COUNT 0
#define WS_PROBS 512
#define WS_TOK   16384
#define WS_WGT   (WS_TOK + E_NUM * T_TOKENS * 4)
#define WS_INV   (WS_WGT + E_NUM * T_TOKENS * 4)
#define WS_W1B   (1ull << 20)
#define WS_W2B   (WS_W1B + 16777216ull)
#define WS_XG    (WS_W2B + 16777216ull)
#define WS_HG    (WS_XG + (unsigned long long)SLOT_CAP * D_DIM * 2)
#define WS_OG    (WS_HG + (unsigned long long)SLOT_CAP * F_DIM * 2)
#define OG_BYTES ((unsigned long long)SLOT_CAP * D_DIM * 4)
// single-Og end ~152 MiB; K-split needs WS_OG + 2*OG_BYTES ~186 MiB (runtime-gated)

// prefix offsets over 128-padded per-expert counts
__device__ __forceinline__ void expert_off(const int* __restrict__ count, int e,
                                           int& off_e, int& cnt_e) {
    int off = 0, ce = 0;
#pragma unroll
    for (int i = 0; i < E_NUM; ++i) {
        int c = count[i];
        if (i == e) ce = c;
        if (i < e) off += (c + 127) & ~127;
    }
    off_e = off; cnt_e = ce;
}

// ---------------------------------------------------------------------------
// Convert w1/w2 fp32 -> bf16 in MFMA B-fragment order (K-inner):
//   frag-lane linear = ((e*(N/16) + ft)*(K/32) + ks)*64 + L   (short8 units)
// Also zeroes count[], probs_g[].
// ---------------------------------------------------------------------------
__global__ __launch_bounds__(256) void moe_convert(
    const float* __restrict__ w1, const float* __restrict__ w2,
    unsigned short* __restrict__ w1b, unsigned short* __restrict__ w2b,
    int* __restrict__ count, float* __restrict__ probs_g)
{
    __shared__ float ts[32][65];
    int tid = threadIdx.x;
    if (blockIdx.x == 0 && tid < E_NUM) { count[tid] = 0; probs_g[tid] = 0.f; }

    int b = blockIdx.x;
    bool is2 = b >= 4096;
    int o = is2 ? b - 4096 : b;
    int e = o >> 9, r = o & 511;
    int N  = is2 ? 512 : 2048;
    int Ks = is2 ? 64 : 16;
    int ng, ks;
    if (!is2) { ng = r & 31; ks = r >> 5; }
    else      { ng = r & 7;  ks = r >> 3; }

    const float* src = (is2 ? w2 : w1) + ((size_t)e << 20) + (size_t)(ks * 32) * N + ng * 64;
    int row = tid >> 3, c4 = (tid & 7) * 4;
    f32x4 v0 = *(const f32x4*)(src + (size_t)row * N + c4);
    f32x4 v1 = *(const f32x4*)(src + (size_t)row * N + c4 + 32);
    *(f32x4*)&ts[row][c4] = v0;
    *(f32x4*)&ts[row][c4 + 32] = v1;
    __syncthreads();

    int f = tid >> 6, L = tid & 63, q = L >> 4, n = L & 15;
    float v[8];
#pragma unroll
    for (int j = 0; j < 8; ++j) v[j] = ts[q * 8 + j][f * 16 + n];
    uint4 pk;
    pk.x = pack2(v[0], v[1]); pk.y = pack2(v[2], v[3]);
    pk.z = pack2(v[4], v[5]); pk.w = pack2(v[6], v[7]);
    size_t fraglane = ((size_t)((e * (N / 16) + ng * 4 + f) * Ks + ks)) * 64 + L;
    unsigned short* dst = (is2 ? w2b : w1b) + fraglane * 8;
    *(uint4*)dst = pk;
}

// ---------------------------------------------------------------------------
// Router. Also emits per-token inverse map inv[t*2+k] = (e<<16)|global_slot.
// ---------------------------------------------------------------------------
__global__ __launch_bounds__(256) void moe_router(
    const float* __restrict__ x, const float* __restrict__ gw,
    int* __restrict__ count, int* __restrict__ tok_list,
    float* __restrict__ wgt_list, float* __restrict__ probs_g,
    int* __restrict__ inv)
{
    __shared__ float pprob[E_NUM];
    __shared__ int   lcnt[E_NUM];
    __shared__ int   gbase[E_NUM];
    __shared__ int   ltok[E_NUM][64];
    __shared__ float lwgt[E_NUM][64];
    __shared__ unsigned char re1[32], re2[32];
    __shared__ short rs1[32], rs2[32];

    int tid = threadIdx.x;
    if (tid < E_NUM) { pprob[tid] = 0.f; lcnt[tid] = 0; }
    __syncthreads();

    int wv = tid >> 6, lane = tid & 63;

    float gr[64];
    {
        const f32x4* gp = (const f32x4*)(gw + lane * 64);
#pragma unroll
        for (int i = 0; i < 16; ++i) *(f32x4*)&gr[i * 4] = gp[i];
    }

    float wps[E_NUM];
#pragma unroll
    for (int e = 0; e < E_NUM; ++e) wps[e] = 0.f;

#pragma unroll 1
    for (int i = 0; i < 8; ++i) {
        int t = blockIdx.x * 32 + wv * 8 + i;
        const float* xp = x + (size_t)t * D_DIM + lane * 8;
        f32x4 x0 = *(const f32x4*)xp;
        f32x4 x1 = *(const f32x4*)(xp + 4);
        float xv[8] = { x0.x, x0.y, x0.z, x0.w, x1.x, x1.y, x1.z, x1.w };
        float acc[E_NUM];
#pragma unroll
        for (int e = 0; e < E_NUM; ++e) acc[e] = 0.f;
#pragma unroll
        for (int j = 0; j < 8; ++j)
#pragma unroll
            for (int e = 0; e < E_NUM; ++e) acc[e] += xv[j] * gr[j * 8 + e];
#pragma unroll
        for (int off = 1; off < 64; off <<= 1)
#pragma unroll
            for (int e = 0; e < E_NUM; ++e) acc[e] += __shfl_xor(acc[e], off);

        float m = acc[0];
#pragma unroll
        for (int e = 1; e < E_NUM; ++e) m = fmaxf(m, acc[e]);
        float p[E_NUM], s = 0.f;
#pragma unroll
        for (int e = 0; e < E_NUM; ++e) { p[e] = __expf(acc[e] - m); s += p[e]; }
        float invs = 1.f / s;
#pragma unroll
        for (int e = 0; e < E_NUM; ++e) { p[e] *= invs; wps[e] += p[e]; }

        int e1 = 0;
#pragma unroll
        for (int e = 1; e < E_NUM; ++e) if (p[e] > p[e1]) e1 = e;
        int e2 = (e1 == 0) ? 1 : 0;
#pragma unroll
        for (int e = 0; e < E_NUM; ++e) if (e != e1 && p[e] > p[e2]) e2 = e;

        if (lane == 0) {
            float invw = 1.f / (p[e1] + p[e2]);
            int s1 = atomicAdd(&lcnt[e1], 1); ltok[e1][s1] = t; lwgt[e1][s1] = p[e1] * invw;
            int s2 = atomicAdd(&lcnt[e2], 1); ltok[e2][s2] = t; lwgt[e2][s2] = p[e2] * invw;
            int li = wv * 8 + i;
            re1[li] = (unsigned char)e1; rs1[li] = (short)s1;
            re2[li] = (unsigned char)e2; rs2[li] = (short)s2;
        }
    }
    if (lane == 0) {
#pragma unroll
        for (int e = 0; e < E_NUM; ++e) atomicAdd(&pprob[e], wps[e]);
    }
    __syncthreads();
    if (tid < E_NUM) {
        gbase[tid] = atomicAdd(&count[tid], lcnt[tid]);
        atomicAdd(&probs_g[tid], pprob[tid]);
    }
    __syncthreads();
    if (tid < 32) {
        int t = blockIdx.x * 32 + tid;
        inv[t * 2]     = ((int)re1[tid] << 16) | (gbase[re1[tid]] + rs1[tid]);
        inv[t * 2 + 1] = ((int)re2[tid] << 16) | (gbase[re2[tid]] + rs2[tid]);
    }
    int ee = tid >> 5;
    for (int ss = tid & 31; ss < lcnt[ee]; ss += 32) {
        int dst = ee * T_TOKENS + gbase[ee] + ss;
        tok_list[dst] = ltok[ee][ss];
        wgt_list[dst] = lwgt[ee][ss];
    }
}

// ---------------------------------------------------------------------------
// Gather: expert-ordered Xg (bf16, A-frag order, K-inner), zero-padded:
//   Xg short8-linear = (slot16*16 + kb)*64 + lane; lane = (m&15) + 16*((k>>3)&3)
// ---------------------------------------------------------------------------
__global__ __launch_bounds__(256) void moe_gather(
    const float* __restrict__ x, const int* __restrict__ count,
    const int* __restrict__ tok_list, unsigned short* __restrict__ Xg,
    const float* __restrict__ probs_g, float* __restrict__ y)
{
    if (blockIdx.x == 0 && threadIdx.x == 0) {
        float s = 0.f;
#pragma unroll
        for (int i = 0; i < E_NUM; ++i) {
            float m = probs_g[i] / (float)T_TOKENS;
            s += m * m;
        }
        y[(size_t)T_TOKENS * D_DIM] = (float)E_NUM * s;
    }

    int e = blockIdx.x & 7, tile = blockIdx.x >> 3;
    int off_e, cnt;
    expert_off(count, e, off_e, cnt);
    int padcnt = (cnt + 127) & ~127;
    if (tile * 64 >= padcnt) return;

    int tid = threadIdx.x;
    int tl = tid >> 2;               // slot in tile 0..63
    int kq = tid & 3;                // 128-k quarter
    int slot = tile * 64 + tl;
    bool valid = slot < cnt;
    int tok = valid ? tok_list[e * T_TOKENS + slot] : 0;
    const float* xr = x + (size_t)tok * D_DIM + kq * 128;
    int base16 = ((off_e + tile * 64) >> 4) + (tl >> 4);
    int mlane = tl & 15;

#pragma unroll 4
    for (int g = 0; g < 16; ++g) {
        uint4 pk;
        if (valid) {
            f32x4 v0 = *(const f32x4*)(xr + g * 8);
            f32x4 v1 = *(const f32x4*)(xr + g * 8 + 4);
            pk.x = pack2(v0.x, v0.y); pk.y = pack2(v0.z, v0.w);
            pk.z = pack2(v1.x, v1.y); pk.w = pack2(v1.z, v1.w);
        } else {
            pk.x = 0; pk.y = 0; pk.z = 0; pk.w = 0;
        }
        int kb = kq * 4 + (g >> 2);
        int lane = mlane + 16 * (g & 3);
        *(uint4*)(Xg + ((size_t)(base16 * 16 + kb) * 64 + lane) * 8) = pk;
    }
}

// ---------------------------------------------------------------------------
// GEMM1: Hg = gelu(Xg @ W1 + b1).  Block 128x128, 4 waves (wave 64x64).
// m97 STRUCTURE: per BK=64 K-step, stage A(16KB)+B(16KB) via global_load_lds
// (32 runs x 1KB, 8/wave; layouts frag-linear so LDS dest is linear), then
// barrier -> 2x(8 ds_read_b128 + 16 MFMA) -> barrier.  XCD-chunked swizzle,
// nt innermost.  SWAPPED operands -> D[f][m]; LIGHT pair-interleaved epilogue
// (no LDS transpose; Hg comes out bit-identical to frag-linear).
// ---------------------------------------------------------------------------
__global__ __launch_bounds__(256) void moe_gemm1(
    const unsigned short* __restrict__ Xg, const unsigned short* __restrict__ w1b,
    const float* __restrict__ b1, const int* __restrict__ count,
    unsigned short* __restrict__ Hg)
{
    int l = (blockIdx.x & 7) * 1024 + (blockIdx.x >> 3);
    int e = l >> 10;
    int rem = l & 1023;
    int mt = rem >> 4, nt = rem & 15;
    int off_e, cnt;
    expert_off(count, e, off_e, cnt);
    if (mt * 128 >= cnt) return;

    __shared__ __align__(16) unsigned short Alds[8192];   // 16 KB: [s16 0..7][kb 0..1][lane][8]
    __shared__ __align__(16) unsigned short Blds[8192];

    int tid = threadIdx.x;
    int wv = tid >> 6, lane = tid & 63;
    int wh = wv >> 1, nh = wv & 1;
    int q = lane >> 4, n = lane & 15;

    int slot16b = (off_e >> 4) + mt * 8;                  // block A base (8 slot16)
    const short8* Ag = (const short8*)Xg + (size_t)slot16b * 1024;
    const short8* Bg = (const short8*)w1b + (size_t)(e * 128 + nt * 8) * 1024;

    f32x4 acc[4][4];   // [j(f-tile)][i(m-tile)]
#pragma unroll
    for (int j = 0; j < 4; ++j)
#pragma unroll
        for (int i = 0; i < 4; ++i) acc[j][i] = (f32x4){0.f, 0.f, 0.f, 0.f};

#pragma unroll 1
    for (int kt = 0; kt < 8; ++kt) {
        // stage 32 KB: run idx 0..15 = A (s=idx>>1, kbi=idx&1), 16..31 = B
#pragma unroll
        for (int rr = 0; rr < 8; ++rr) {
            int idx = wv * 8 + rr;
            int isB = idx >> 4;
            int s = (idx & 15) >> 1, kbi = idx & 1;
            const short8* g = (isB ? Bg : Ag) + (size_t)s * 1024 + (kt * 2 + kbi) * 64 + lane;
            unsigned short* ld = (isB ? Blds : Alds) + (size_t)((s * 2 + kbi) * 64) * 8;
            gload_lds16((const void*)g, (void*)ld);
        }
        __syncthreads();   // drains vmcnt -> staged LDS visible

#pragma unroll
        for (int kbi = 0; kbi < 2; ++kbi) {
            short8 A[4], B[4];
#pragma unroll
            for (int i = 0; i < 4; ++i)
                A[i] = *(const short8*)(Alds + (size_t)((((wh * 4 + i) * 2 + kbi) * 64 + lane)) * 8);
#pragma unroll
            for (int j = 0; j < 4; ++j)
                B[j] = *(const short8*)(Blds + (size_t)((((nh * 4 + j) * 2 + kbi) * 64 + lane)) * 8);
#pragma unroll
            for (int j = 0; j < 4; ++j)
#pragma unroll
                for (int i = 0; i < 4; ++i)
                    acc[j][i] = __builtin_amdgcn_mfma_f32_16x16x32_bf16(B[j], A[i], acc[j][i], 0, 0, 0);
        }
        __syncthreads();   // LDS reusable next K-step
    }

    // epilogue: pack 4 consecutive f (rr) for fixed m -> pair-interleaved 8B store
    s16x4* Hg8 = (s16x4*)Hg;
    int q1 = q >> 1, q0 = q & 1;
    int slot16w = slot16b + wh * 4;
#pragma unroll
    for (int j = 0; j < 4; ++j) {
        f32x4 bb = *(const f32x4*)(b1 + e * F_DIM + nt * 128 + nh * 64 + j * 16 + q * 4);
        int ftile = nt * 8 + nh * 4 + j;
#pragma unroll
        for (int i = 0; i < 4; ++i) {
            s16x4 sv;
#pragma unroll
            for (int rr = 0; rr < 4; ++rr)
                sv[rr] = (short)f2bf(gelu_fast(acc[j][i][rr] + bb[rr]));
            Hg8[(size_t)(slot16w + i) * 8192 + ftile * 64 + q1 * 32 + 2 * n + q0] = sv;
        }
    }
}

// ---------------------------------------------------------------------------
// GEMM2: Og[slot] = wgt * (Hg @ W2 + b2).  Block 128x128, 4 waves; same m97
// staging structure; optional K-split x2 (kt0 -> Og0 with +b2, kt1 -> Og1).
// A-frags from frag-linear Hg; SWAPPED operands -> D[d][m] -> f32x4 stores.
// ---------------------------------------------------------------------------
__global__ __launch_bounds__(256) void moe_gemm2(
    const unsigned short* __restrict__ Hg, const unsigned short* __restrict__ w2b,
    const float* __restrict__ b2, const int* __restrict__ count,
    const float* __restrict__ wgt_list, float* __restrict__ Og0,
    float* __restrict__ Og1, int ksplit)
{
    int e, kt, mt, nt;
    if (ksplit) {
        int l = (blockIdx.x & 7) * 512 + (blockIdx.x >> 3);
        e = l >> 9;
        int rem = l & 511;
        mt = rem >> 3; kt = (rem >> 2) & 1; nt = rem & 3;
    } else {
        int l = (blockIdx.x & 7) * 256 + (blockIdx.x >> 3);
        e = l >> 8;
        int rem = l & 255;
        mt = rem >> 2; kt = 0; nt = rem & 3;
    }
    int off_e, cnt;
    expert_off(count, e, off_e, cnt);
    if (mt * 128 >= cnt) return;

    __shared__ __align__(16) unsigned short Alds[8192];
    __shared__ __align__(16) unsigned short Blds[8192];
    __shared__ float swgt[128];

    int tid = threadIdx.x;
    if (tid < 128) {
        int s = mt * 128 + tid;
        swgt[tid] = (s < cnt) ? wgt_list[e * T_TOKENS + s] : 0.f;
    }

    int wv = tid >> 6, lane = tid & 63;
    int wh = wv >> 1, nh = wv & 1;
    int q = lane >> 4, n = lane & 15;

    int nsteps = ksplit ? 16 : 32;       // BK=64 steps over K half / full
    int kb0 = kt * 32;

    int slot16b = (off_e >> 4) + mt * 8;
    const short8* Ag = (const short8*)Hg + (size_t)slot16b * 4096;
    const short8* Bg = (const short8*)w2b + (size_t)(e * 32 + nt * 8) * 4096;

    f32x4 acc[4][4];   // [j(d-tile)][i(m-tile)]
#pragma unroll
    for (int j = 0; j < 4; ++j)
#pragma unroll
        for (int i = 0; i < 4; ++i) acc[j][i] = (f32x4){0.f, 0.f, 0.f, 0.f};

#pragma unroll 1
    for (int kss = 0; kss < nsteps; ++kss) {
#pragma unroll
        for (int rr = 0; rr < 8; ++rr) {
            int idx = wv * 8 + rr;
            int isB = idx >> 4;
            int s = (idx & 15) >> 1, kbi = idx & 1;
            int kb = kb0 + kss * 2 + kbi;
            const short8* g = (isB ? Bg : Ag) + (size_t)s * 4096 + kb * 64 + lane;
            unsigned short* ld = (isB ? Blds : Alds) + (size_t)((s * 2 + kbi) * 64) * 8;
            gload_lds16((const void*)g, (void*)ld);
        }
        __syncthreads();

#pragma unroll
        for (int kbi = 0; kbi < 2; ++kbi) {
            short8 A[4], B[4];
#pragma unroll
            for (int i = 0; i < 4; ++i)
                A[i] = *(const short8*)(Alds + (size_t)((((wh * 4 + i) * 2 + kbi) * 64 + lane)) * 8);
#pragma unroll
            for (int j = 0; j < 4; ++j)
                B[j] = *(const short8*)(Blds + (size_t)((((nh * 4 + j) * 2 + kbi) * 64 + lane)) * 8);
#pragma unroll
            for (int j = 0; j < 4; ++j)
#pragma unroll
                for (int i = 0; i < 4; ++i)
                    acc[j][i] = __builtin_amdgcn_mfma_f32_16x16x32_bf16(B[j], A[i], acc[j][i], 0, 0, 0);
        }
        __syncthreads();
    }

    // epilogue: lane holds 4 consecutive d for fixed slot m -> f32x4 stores
    float* Og = (kt == 0) ? Og0 : Og1;
#pragma unroll
    for (int j = 0; j < 4; ++j) {
        int d0 = nt * 128 + nh * 64 + j * 16 + q * 4;
        f32x4 bb;
        if (kt == 0) bb = *(const f32x4*)(b2 + e * D_DIM + d0);
        else         bb = (f32x4){0.f, 0.f, 0.f, 0.f};
#pragma unroll
        for (int i = 0; i < 4; ++i) {
            int m = wh * 64 + i * 16 + n;
            float wg = swgt[m];
            f32x4 o;
#pragma unroll
            for (int rr = 0; rr < 4; ++rr) o[rr] = wg * (acc[j][i][rr] + bb[rr]);
            *(f32x4*)(Og + (size_t)(off_e + mt * 128 + m) * D_DIM + d0) = o;
        }
    }
}

// ---------------------------------------------------------------------------
// Combine: y[t] = sum over its 2 expert rows (and 2 K-halves when split).
// ---------------------------------------------------------------------------
__global__ __launch_bounds__(256) void moe_combine(
    const float* __restrict__ Og0, const float* __restrict__ Og1,
    const int* __restrict__ inv, const int* __restrict__ count,
    float* __restrict__ y, int ksplit)
{
    __shared__ int offs[E_NUM];
    int tid = threadIdx.x;
    if (tid < E_NUM) {
        int off = 0;
        for (int i = 0; i < tid; ++i) off += (count[i] + 127) & ~127;
        offs[tid] = off;
    }
    __syncthreads();

    int tk = blockIdx.x * 2 + (tid >> 7);
    int l = tid & 127;
    int i1 = inv[tk * 2], i2 = inv[tk * 2 + 1];
    size_t r1 = (size_t)(offs[i1 >> 16] + (i1 & 0xffff)) * D_DIM;
    size_t r2 = (size_t)(offs[i2 >> 16] + (i2 & 0xffff)) * D_DIM;
    f32x4 a = *((const f32x4*)(Og0 + r1) + l);
    f32x4 b = *((const f32x4*)(Og0 + r2) + l);
    f32x4 o = { a.x + b.x, a.y + b.y, a.z + b.z, a.w + b.w };
    if (ksplit) {
        f32x4 c = *((const f32x4*)(Og1 + r1) + l);
        f32x4 d = *((const f32x4*)(Og1 + r2) + l);
        o.x += c.x + d.x; o.y += c.y + d.y; o.z += c.z + d.z; o.w += c.w + d.w;
    }
    *((f32x4*)(y + (size_t)tk * D_DIM) + l) = o;
}

// ---------------------------------------------------------------------------
extern "C" void kernel_launch(void* const* d_in, const int* in_sizes, int n_in,
                              void* d_out, int out_size, void* d_ws, size_t ws_size,
                              hipStream_t stream) {
    const float* x  = (const float*)d_in[0];
    const float* gw = (const float*)d_in[1];
    const float* w1 = (const float*)d_in[2];
    const float* b1 = (const float*)d_in[3];
    const float* w2 = (const float*)d_in[4];
    const float* b2 = (const float*)d_in[5];
    float* out = (float*)d_out;

    char* ws = (char*)d_ws;
    int*   count     = (int*)(ws + WS_COUNT);
    float* probs_g   = (float*)(ws + WS_PROBS);
    int*   tok_list  = (int*)(ws + WS_TOK);
    float* wgt_list  = (float*)(ws + WS_WGT);
    int*   inv       = (int*)(ws + WS_INV);
    unsigned short* w1b = (unsigned short*)(ws + WS_W1B);
    unsigned short* w2b = (unsigned short*)(ws + WS_W2B);
    unsigned short* Xg  = (unsigned short*)(ws + WS_XG);
    unsigned short* Hg  = (unsigned short*)(ws + WS_HG);
    float*          Og0 = (float*)(ws + WS_OG);
    float*          Og1 = (float*)(ws + WS_OG + OG_BYTES);

    int ksplit = (ws_size >= WS_OG + 2 * OG_BYTES) ? 1 : 0;

    moe_convert<<<8192, 256, 0, stream>>>(w1, w2, w1b, w2b, count, probs_g);
    moe_router<<<T_TOKENS / 32, 256, 0, stream>>>(x, gw, count, tok_list, wgt_list, probs_g, inv);
    moe_gather<<<8 * 128, 256, 0, stream>>>(x, count, tok_list, Xg, probs_g, out);
    moe_gemm1<<<8192, 256, 0, stream>>>(Xg, w1b, b1, count, Hg);
    moe_gemm2<<<(ksplit ? 4096 : 2048), 256, 0, stream>>>(Hg, w2b, b2, count, wgt_list, Og0, Og1, ksplit);
    moe_combine<<<T_TOKENS / 2, 256, 0, stream>>>(Og0, Og1, inv, count, out, ksplit);
}